// Round 9
// baseline (422.322 us; speedup 1.0000x reference)
//
#include <hip/hip_runtime.h>

#define NODES 50000
#define RELS  3
#define NEDGE 600000
#define FIN   128
#define FHID  64
#define FOUT  64
#define SEGS  (RELS * NODES)            // 150000 (rel, dst) segments
#define NBLK  ((SEGS + 255) / 256)      // 586 scan blocks

#define HC     32                       // histogram chunks per edge array
#define HCHUNK (NEDGE / HC)             // 18750 (exact)
#define HWORDS 16384                    // 32768 u16 bins packed in u32 words (64 KB LDS)

typedef _Float16 half8 __attribute__((ext_vector_type(8)));
typedef float   floatx4 __attribute__((ext_vector_type(4)));

// ---------------- LDS-staged histogram: no global atomics ----------------
__global__ __launch_bounds__(256) void hist_kernel(const int* __restrict__ src,
                                                   const int* __restrict__ dst,
                                                   unsigned int* __restrict__ slab32) {
    __shared__ unsigned int bins[HWORDS];          // 64 KB, u16-packed counts
    int chunk = blockIdx.x, job = blockIdx.y, rg = blockIdx.z;
    const int* arr = (job < 3 ? src + (size_t)job * NEDGE
                              : dst + (size_t)(job - 3) * NEDGE) + (size_t)chunk * HCHUNK;
    for (int w = threadIdx.x; w < HWORDS; w += 256) bins[w] = 0u;
    __syncthreads();
    for (int i = threadIdx.x; i < HCHUNK; i += 256) {
        int v = arr[i];
        if ((v >> 15) == rg) {
            int b = v & 32767;
            atomicAdd(&bins[b >> 1], 1u << ((b & 1) * 16));   // LDS, no return
        }
    }
    __syncthreads();
    unsigned int* out = slab32 + ((size_t)((job * 2 + rg) * HC + chunk)) * HWORDS;
    for (int w = threadIdx.x; w < HWORDS; w += 256) out[w] = bins[w];
}

// ---------------- slab reduce -> degrees/norms (+ fused weight fp16 transpose)
__global__ __launch_bounds__(256) void degnorm_kernel(unsigned short* __restrict__ slab16,
                                                      int* __restrict__ idI,
                                                      float* __restrict__ outnorm,
                                                      float* __restrict__ innorm,
                                                      const float* __restrict__ W1,
                                                      const float* __restrict__ W2,
                                                      _Float16* __restrict__ W1t,
                                                      _Float16* __restrict__ W2t) {
    int gid = blockIdx.x * 256 + threadIdx.x;
    if (gid < 6 * NODES) {
        int j = gid / NODES, node = gid - j * NODES;
        int rg = node >> 15, b = node & 32767;
        size_t base = ((size_t)((j * 2 + rg) * HC)) << 15;
        if (j < 3) {
            int sum = 0;
#pragma unroll 4
            for (int c = 0; c < HC; ++c) sum += slab16[base + ((size_t)c << 15) + b];
            outnorm[j * NODES + node] = rsqrtf(fmaxf((float)sum, 1.0f));
        } else {
            int run = 0;
#pragma unroll 4
            for (int c = 0; c < HC; ++c) {
                size_t idx = base + ((size_t)c << 15) + b;
                int v = slab16[idx];
                slab16[idx] = (unsigned short)run;
                run += v;
            }
            idI[(j - 3) * NODES + node] = run;
            innorm[(j - 3) * NODES + node] = rsqrtf(fmaxf((float)run, 1.0f));
        }
        return;
    }
    int g2 = gid - 6 * NODES;
    if (g2 < RELS * FIN * FHID) {                  // W1 -> fp16 [r][j][k]
        int r = g2 / (FIN * FHID);
        int rem = g2 - r * FIN * FHID;
        int k = rem / FHID, j = rem - k * FHID;
        W1t[((size_t)r * FHID + j) * FIN + k] = (_Float16)W1[g2];
        return;
    }
    int g3 = g2 - RELS * FIN * FHID;
    if (g3 < RELS * FHID * FOUT) {                 // W2 -> fp16 [r][j][k]
        int r = g3 / (FHID * FOUT);
        int rem = g3 - r * FHID * FOUT;
        int k = rem / FOUT, j = rem - k * FOUT;
        W2t[((size_t)r * FOUT + j) * FHID + k] = (_Float16)W2[g3];
    }
}

// ---------------- scan step 1: per-block sums ----------------
__global__ __launch_bounds__(256) void scan_sums_kernel(const int* __restrict__ idI,
                                                        int* __restrict__ partials) {
    __shared__ int s[256];
    int i = blockIdx.x * 256 + threadIdx.x;
    s[threadIdx.x] = (i < SEGS) ? idI[i] : 0;
    __syncthreads();
    for (int off = 128; off > 0; off >>= 1) {
        if (threadIdx.x < off) s[threadIdx.x] += s[threadIdx.x + off];
        __syncthreads();
    }
    if (threadIdx.x == 0) partials[blockIdx.x] = s[0];
}

// ---------------- scan step 2: each block re-scans raw partials in LDS, then block scan
__global__ __launch_bounds__(256) void scan_write_kernel(const int* __restrict__ idI,
                                                         const int* __restrict__ partials,
                                                         int* __restrict__ offs) {
    __shared__ int sp[1024];
    __shared__ int s[256];
    int tid = threadIdx.x;
    for (int i = tid; i < 1024; i += 256) sp[i] = (i < NBLK) ? partials[i] : 0;
    __syncthreads();
    for (int off = 1; off < 1024; off <<= 1) {
        int v[4];
#pragma unroll
        for (int k = 0; k < 4; ++k) { int i = tid + k * 256; v[k] = (i >= off) ? sp[i - off] : 0; }
        __syncthreads();
#pragma unroll
        for (int k = 0; k < 4; ++k) sp[tid + k * 256] += v[k];
        __syncthreads();
    }
    int bpre = (blockIdx.x == 0) ? 0 : sp[blockIdx.x - 1];   // exclusive prefix of this block
    int i = blockIdx.x * 256 + tid;
    int v = (i < SEGS) ? idI[i] : 0;
    s[tid] = v;
    __syncthreads();
    for (int off = 1; off < 256; off <<= 1) {
        int t = s[tid];
        int add = (tid >= off) ? s[tid - off] : 0;
        __syncthreads();
        s[tid] = t + add;
        __syncthreads();
    }
    if (i < SEGS) offs[i] = bpre + (s[tid] - v);
}

// ---------------- CSR fill via LDS cursors + per-chunk slab prefixes ----------------
__global__ __launch_bounds__(256) void fill2_kernel(const int* __restrict__ src,
                                                    const int* __restrict__ dst,
                                                    const int* __restrict__ offs,
                                                    const unsigned short* __restrict__ slab16,
                                                    int* __restrict__ edge_src) {
    __shared__ unsigned int cur[HWORDS];           // 64 KB u16-packed cursors
    int chunk = blockIdx.x, r = blockIdx.y, rg = blockIdx.z;
    for (int w = threadIdx.x; w < HWORDS; w += 256) cur[w] = 0u;
    __syncthreads();
    size_t ebase = (size_t)r * NEDGE + (size_t)chunk * HCHUNK;
    const unsigned short* pre = slab16 + (((size_t)(((3 + r) * 2 + rg) * HC + chunk)) << 15);
    for (int i = threadIdx.x; i < HCHUNK; i += 256) {
        int d = dst[ebase + i];
        if ((d >> 15) == rg) {
            int b = d & 32767;
            unsigned int old = atomicAdd(&cur[b >> 1], 1u << ((b & 1) * 16));
            int local = (int)((old >> ((b & 1) * 16)) & 0xffffu);
            int pos = offs[r * NODES + d] + (int)pre[b] + local;
            edge_src[pos] = src[ebase + i];
        }
    }
}

// ---------------- layer 1 GEMM via MFMA fp16, sliced-output layout ----------------
// h2[slice][rel][node][8cols] fp16: slice = j>>3. Wave = 16 nodes x 192 cols.
__global__ __launch_bounds__(256, 4) void gemm1_kernel(const float* __restrict__ x,
                                                       const _Float16* __restrict__ W1t,
                                                       const float* __restrict__ outnorm,
                                                       _Float16* __restrict__ h2) {
    int lane = threadIdx.x & 63;
    int wv   = threadIdx.x >> 6;
    int m = lane & 15, quad = lane >> 4;
    int n0 = (blockIdx.x * 4 + wv) * 16;
    if (n0 + 16 > NODES) n0 = NODES - 16;          // tail waves duplicate rows (same values)
    const float* xrow = x + (size_t)(n0 + m) * FIN + quad * 8;

    floatx4 acc[12];
#pragma unroll
    for (int t = 0; t < 12; ++t) acc[t] = (floatx4){0.f, 0.f, 0.f, 0.f};

#pragma unroll 1
    for (int ks = 0; ks < 4; ++ks) {               // K step of 32
        float4 xa = *(const float4*)(xrow + ks * 32);
        float4 xb = *(const float4*)(xrow + ks * 32 + 4);
        half8 a;
        a[0] = (_Float16)xa.x; a[1] = (_Float16)xa.y;
        a[2] = (_Float16)xa.z; a[3] = (_Float16)xa.w;
        a[4] = (_Float16)xb.x; a[5] = (_Float16)xb.y;
        a[6] = (_Float16)xb.z; a[7] = (_Float16)xb.w;
#pragma unroll
        for (int jt = 0; jt < 12; ++jt) {          // W1t flat: [192][128]
            const _Float16* bp = W1t + ((size_t)jt * 16 + m) * FIN + ks * 32 + quad * 8;
            half8 b = *(const half8*)bp;
            acc[jt] = __builtin_amdgcn_mfma_f32_16x16x32_f16(a, b, acc[jt], 0, 0, 0);
        }
    }

#pragma unroll
    for (int jt = 0; jt < 12; ++jt) {
        int r = jt >> 2;
        int j = (jt & 3) * 16 + m;                 // D col = lane&15
        int sl = j >> 3, col = j & 7;
        const float* on = outnorm + r * NODES;
        _Float16* hb = h2 + ((size_t)(sl * RELS + r) * NODES) * 8 + col;
#pragma unroll
        for (int reg = 0; reg < 4; ++reg) {
            int node = n0 + quad * 4 + reg;        // D row = quad*4+reg
            hb[(size_t)node * 8] = (_Float16)(acc[jt][reg] * on[node]);
        }
    }
}

// ---------------- layer 1 gather, sliced: block slice = blockIdx.x & 7 (XCD swizzle)
// Wave = 8 d-nodes x 8 edge-lanes; 16 B (8 cols) per lane per edge.
__global__ __launch_bounds__(256) void gather1_kernel(const _Float16* __restrict__ h2,
                                                      const int* __restrict__ es,
                                                      const int* __restrict__ offs,
                                                      const int* __restrict__ cnt,
                                                      const float* __restrict__ innorm,
                                                      const float* __restrict__ b1,
                                                      _Float16* __restrict__ B2) {
    int lane = threadIdx.x & 63;
    int wv   = threadIdx.x >> 6;
    int s      = blockIdx.x & 7;                   // slice -> XCD via round-robin dispatch
    int dgroup = blockIdx.x >> 3;
    int dsub = lane >> 3, e8 = lane & 7;
    int d = dgroup * 32 + wv * 8 + dsub;
    if (d >= NODES) d = NODES - 1;                 // duplicate work, benign same-value writes
    float tot[8] = {0.f, 0.f, 0.f, 0.f, 0.f, 0.f, 0.f, 0.f};
#pragma unroll
    for (int r = 0; r < RELS; ++r) {
        int seg = r * NODES + d;
        int o = offs[seg], c = cnt[seg];
        const _Float16* Hs = h2 + ((size_t)(s * RELS + r) * NODES) * 8;
        float acc[8] = {0.f, 0.f, 0.f, 0.f, 0.f, 0.f, 0.f, 0.f};
        for (int t = 0; t + e8 < c; t += 8) {
            int idx = es[o + t + e8];
            half8 v = *(const half8*)(Hs + (size_t)idx * 8);
#pragma unroll
            for (int i = 0; i < 8; ++i) acc[i] += (float)v[i];
        }
        float inr = innorm[seg];
#pragma unroll
        for (int i = 0; i < 8; ++i) tot[i] = fmaf(inr, acc[i], tot[i]);
    }
#pragma unroll
    for (int i = 0; i < 8; ++i) {
        tot[i] += __shfl_xor(tot[i], 1);
        tot[i] += __shfl_xor(tot[i], 2);
        tot[i] += __shfl_xor(tot[i], 4);
    }
    if (e8 == 0) {
        half8 o8;
#pragma unroll
        for (int i = 0; i < 8; ++i) {
            int j = s * 8 + i;
            float bs = b1[j] + b1[FHID + j] + b1[2 * FHID + j];
            o8[i] = (_Float16)fmaxf(tot[i] + bs, 0.f);
        }
        *(half8*)(B2 + ((size_t)s * NODES + d) * 8) = o8;
    }
}

// ---------------- layer 2 gather, sliced; per-rel output A2[slice][rel][node][8]
__global__ __launch_bounds__(256) void gather2_kernel(const _Float16* __restrict__ B2,
                                                      const int* __restrict__ es,
                                                      const int* __restrict__ offs,
                                                      const int* __restrict__ cnt,
                                                      const float* __restrict__ outnorm,
                                                      const float* __restrict__ innorm,
                                                      _Float16* __restrict__ A2) {
    int lane = threadIdx.x & 63;
    int wv   = threadIdx.x >> 6;
    int s      = blockIdx.x & 7;
    int dgroup = blockIdx.x >> 3;
    int dsub = lane >> 3, e8 = lane & 7;
    int d = dgroup * 32 + wv * 8 + dsub;
    if (d >= NODES) d = NODES - 1;
    const _Float16* Bs = B2 + ((size_t)s * NODES) * 8;
#pragma unroll
    for (int r = 0; r < RELS; ++r) {
        int seg = r * NODES + d;
        int o = offs[seg], c = cnt[seg];
        const float* on = outnorm + r * NODES;
        float acc[8] = {0.f, 0.f, 0.f, 0.f, 0.f, 0.f, 0.f, 0.f};
        for (int t = 0; t + e8 < c; t += 8) {
            int idx = es[o + t + e8];
            float w = on[idx];
            half8 v = *(const half8*)(Bs + (size_t)idx * 8);
#pragma unroll
            for (int i = 0; i < 8; ++i) acc[i] = fmaf(w, (float)v[i], acc[i]);
        }
#pragma unroll
        for (int i = 0; i < 8; ++i) {
            acc[i] += __shfl_xor(acc[i], 1);
            acc[i] += __shfl_xor(acc[i], 2);
            acc[i] += __shfl_xor(acc[i], 4);
        }
        if (e8 == 0) {
            float inr = innorm[seg];
            half8 o8;
#pragma unroll
            for (int i = 0; i < 8; ++i) o8[i] = (_Float16)(inr * acc[i]);
            *(half8*)(A2 + ((size_t)(s * RELS + r) * NODES + d) * 8) = o8;
        }
    }
}

// ---------------- layer 2 GEMM via MFMA fp16 (sliced A2 input) ----------------
__global__ __launch_bounds__(256, 4) void out_kernel(const _Float16* __restrict__ A2,
                                                     const _Float16* __restrict__ W2t,
                                                     const float* __restrict__ b2,
                                                     float* __restrict__ out) {
    int lane = threadIdx.x & 63;
    int wv   = threadIdx.x >> 6;
    int m = lane & 15, quad = lane >> 4;
    int n0 = (blockIdx.x * 4 + wv) * 16;
    if (n0 + 16 > NODES) n0 = NODES - 16;

    floatx4 acc[4];
#pragma unroll
    for (int t = 0; t < 4; ++t) acc[t] = (floatx4){0.f, 0.f, 0.f, 0.f};

#pragma unroll 1
    for (int kk = 0; kk < 6; ++kk) {               // (rel, 32-K-step)
        int r = kk >> 1, kb = (kk & 1) * 32;
        int sl = (kb >> 3) + quad;                 // A-frag k = kb + quad*8 + t -> one slice chunk
        const _Float16* ap = A2 + (((size_t)(sl * RELS + r)) * NODES + (n0 + m)) * 8;
        half8 a = *(const half8*)ap;
#pragma unroll
        for (int jt = 0; jt < 4; ++jt) {
            const _Float16* bp = W2t + ((size_t)(r * FOUT + jt * 16 + m)) * FHID + kb + quad * 8;
            half8 b = *(const half8*)bp;
            acc[jt] = __builtin_amdgcn_mfma_f32_16x16x32_f16(a, b, acc[jt], 0, 0, 0);
        }
    }

#pragma unroll
    for (int jt = 0; jt < 4; ++jt) {
        int j = jt * 16 + m;
        float bs = b2[j] + b2[FOUT + j] + b2[2 * FOUT + j];
#pragma unroll
        for (int reg = 0; reg < 4; ++reg) {
            int node = n0 + quad * 4 + reg;
            out[(size_t)node * FOUT + j] = acc[jt][reg] + bs;
        }
    }
}

extern "C" void kernel_launch(void* const* d_in, const int* in_sizes, int n_in,
                              void* d_out, int out_size, void* d_ws, size_t ws_size,
                              hipStream_t stream) {
    const float* x   = (const float*)d_in[0];   // [N,128]
    const float* W1  = (const float*)d_in[1];   // [3,128,64]
    const float* b1  = (const float*)d_in[2];   // [3,64]
    const float* W2  = (const float*)d_in[3];   // [3,64,64]
    const float* b2  = (const float*)d_in[4];   // [3,64]
    const int*   src = (const int*)d_in[5];     // [3,E]
    const int*   dst = (const int*)d_in[6];     // [3,E]
    float* out = (float*)d_out;                 // [N,64]

    // ws: idI | offs | partials | edge_src | outnorm | innorm | W1t | W2t | h2 | B2 | A2
    int*   idI      = (int*)d_ws;
    int*   offs     = idI + SEGS;
    int*   partials = offs + SEGS;
    int*   edge_src = partials + 1024;
    float* outnorm  = (float*)(edge_src + (size_t)RELS * NEDGE);
    float* innorm   = outnorm + SEGS;
    _Float16* W1t   = (_Float16*)(innorm + SEGS);            // [3][64][128]
    _Float16* W2t   = W1t + (size_t)RELS * FHID * FIN;       // [3][64][64]
    _Float16* h2    = W2t + (size_t)RELS * FHID * FOUT;      // [8][3][N][8] fp16 sliced
    _Float16* B2    = h2 + (size_t)SEGS * FHID;              // [8][N][8]  fp16 sliced
    _Float16* A2    = B2 + (size_t)NODES * FHID;             // [8][3][N][8] fp16 sliced
    // 25.2 MB slab aliases h2|B2 (consumed by fill2 before gemm1/gather1 write them)
    unsigned int*   slab32 = (unsigned int*)h2;
    unsigned short* slab16 = (unsigned short*)h2;

    const int GW = ((NODES / 16) + 4) / 4;        // 782 blocks of 4 waves x 16 nodes
    const int GG = ((NODES + 31) / 32) * 8;       // 12504: (d-group) x 8 slices

    // CSR build + norms + weight convert, no global atomics
    hist_kernel<<<dim3(HC, 6, 2), 256, 0, stream>>>(src, dst, slab32);
    degnorm_kernel<<<(6 * NODES + RELS * FIN * FHID + RELS * FHID * FOUT + 255) / 256,
                     256, 0, stream>>>(slab16, idI, outnorm, innorm, W1, W2, W1t, W2t);
    scan_sums_kernel<<<NBLK, 256, 0, stream>>>(idI, partials);
    scan_write_kernel<<<NBLK, 256, 0, stream>>>(idI, partials, offs);
    fill2_kernel<<<dim3(HC, RELS, 2), 256, 0, stream>>>(src, dst, offs, slab16, edge_src);

    // layer 1
    gemm1_kernel<<<GW, 256, 0, stream>>>(x, W1t, outnorm, h2);
    gather1_kernel<<<GG, 256, 0, stream>>>(h2, edge_src, offs, idI, innorm, b1, B2);

    // layer 2
    gather2_kernel<<<GG, 256, 0, stream>>>(B2, edge_src, offs, idI, outnorm, innorm, A2);
    out_kernel<<<GW, 256, 0, stream>>>(A2, W2t, b2, out);
}

// Round 10
// 322.179 us; speedup vs baseline: 1.3108x; 1.3108x over previous
//
#include <hip/hip_runtime.h>

#define NODES 50000
#define RELS  3
#define NEDGE 600000
#define FIN   128
#define FHID  64
#define FOUT  64
#define SEGS  (RELS * NODES)            // 150000 (rel, dst) segments
#define NBLK  ((SEGS + 255) / 256)      // 586 scan blocks

#define HC     32                       // histogram chunks per edge array
#define HCHUNK (NEDGE / HC)             // 18750 (exact)
#define HWORDS 16384                    // 32768 u16 bins packed in u32 words (64 KB LDS)

typedef _Float16 half8 __attribute__((ext_vector_type(8)));
typedef float   floatx4 __attribute__((ext_vector_type(4)));

// ---------------- LDS-staged histogram: no global atomics ----------------
__global__ __launch_bounds__(256) void hist_kernel(const int* __restrict__ src,
                                                   const int* __restrict__ dst,
                                                   unsigned int* __restrict__ slab32) {
    __shared__ unsigned int bins[HWORDS];          // 64 KB, u16-packed counts
    int chunk = blockIdx.x, job = blockIdx.y, rg = blockIdx.z;
    const int* arr = (job < 3 ? src + (size_t)job * NEDGE
                              : dst + (size_t)(job - 3) * NEDGE) + (size_t)chunk * HCHUNK;
    for (int w = threadIdx.x; w < HWORDS; w += 256) bins[w] = 0u;
    __syncthreads();
    for (int i = threadIdx.x; i < HCHUNK; i += 256) {
        int v = arr[i];
        if ((v >> 15) == rg) {
            int b = v & 32767;
            atomicAdd(&bins[b >> 1], 1u << ((b & 1) * 16));   // LDS, no return
        }
    }
    __syncthreads();
    unsigned int* out = slab32 + ((size_t)((job * 2 + rg) * HC + chunk)) * HWORDS;
    for (int w = threadIdx.x; w < HWORDS; w += 256) out[w] = bins[w];
}

// ---------------- slab reduce -> degrees/norms (+ fused weight fp16 transpose)
__global__ __launch_bounds__(256) void degnorm_kernel(unsigned short* __restrict__ slab16,
                                                      int* __restrict__ idI,
                                                      float* __restrict__ outnorm,
                                                      float* __restrict__ innorm,
                                                      const float* __restrict__ W1,
                                                      const float* __restrict__ W2,
                                                      _Float16* __restrict__ W1t,
                                                      _Float16* __restrict__ W2t) {
    int gid = blockIdx.x * 256 + threadIdx.x;
    if (gid < 6 * NODES) {
        int j = gid / NODES, node = gid - j * NODES;
        int rg = node >> 15, b = node & 32767;
        size_t base = ((size_t)((j * 2 + rg) * HC)) << 15;
        if (j < 3) {
            int sum = 0;
#pragma unroll 4
            for (int c = 0; c < HC; ++c) sum += slab16[base + ((size_t)c << 15) + b];
            outnorm[j * NODES + node] = rsqrtf(fmaxf((float)sum, 1.0f));
        } else {
            int run = 0;
#pragma unroll 4
            for (int c = 0; c < HC; ++c) {
                size_t idx = base + ((size_t)c << 15) + b;
                int v = slab16[idx];
                slab16[idx] = (unsigned short)run;
                run += v;
            }
            idI[(j - 3) * NODES + node] = run;
            innorm[(j - 3) * NODES + node] = rsqrtf(fmaxf((float)run, 1.0f));
        }
        return;
    }
    int g2 = gid - 6 * NODES;
    if (g2 < RELS * FIN * FHID) {                  // W1 -> fp16 [r][j][k]
        int r = g2 / (FIN * FHID);
        int rem = g2 - r * FIN * FHID;
        int k = rem / FHID, j = rem - k * FHID;
        W1t[((size_t)r * FHID + j) * FIN + k] = (_Float16)W1[g2];
        return;
    }
    int g3 = g2 - RELS * FIN * FHID;
    if (g3 < RELS * FHID * FOUT) {                 // W2 -> fp16 [r][j][k]
        int r = g3 / (FHID * FOUT);
        int rem = g3 - r * FHID * FOUT;
        int k = rem / FOUT, j = rem - k * FOUT;
        W2t[((size_t)r * FOUT + j) * FHID + k] = (_Float16)W2[g3];
    }
}

// ---------------- scan step 1: per-block sums ----------------
__global__ __launch_bounds__(256) void scan_sums_kernel(const int* __restrict__ idI,
                                                        int* __restrict__ partials) {
    __shared__ int s[256];
    int i = blockIdx.x * 256 + threadIdx.x;
    s[threadIdx.x] = (i < SEGS) ? idI[i] : 0;
    __syncthreads();
    for (int off = 128; off > 0; off >>= 1) {
        if (threadIdx.x < off) s[threadIdx.x] += s[threadIdx.x + off];
        __syncthreads();
    }
    if (threadIdx.x == 0) partials[blockIdx.x] = s[0];
}

// ---------------- scan step 2: each block re-scans raw partials in LDS, then block scan
__global__ __launch_bounds__(256) void scan_write_kernel(const int* __restrict__ idI,
                                                         const int* __restrict__ partials,
                                                         int* __restrict__ offs) {
    __shared__ int sp[1024];
    __shared__ int s[256];
    int tid = threadIdx.x;
    for (int i = tid; i < 1024; i += 256) sp[i] = (i < NBLK) ? partials[i] : 0;
    __syncthreads();
    for (int off = 1; off < 1024; off <<= 1) {
        int v[4];
#pragma unroll
        for (int k = 0; k < 4; ++k) { int i = tid + k * 256; v[k] = (i >= off) ? sp[i - off] : 0; }
        __syncthreads();
#pragma unroll
        for (int k = 0; k < 4; ++k) sp[tid + k * 256] += v[k];
        __syncthreads();
    }
    int bpre = (blockIdx.x == 0) ? 0 : sp[blockIdx.x - 1];   // exclusive prefix of this block
    int i = blockIdx.x * 256 + tid;
    int v = (i < SEGS) ? idI[i] : 0;
    s[tid] = v;
    __syncthreads();
    for (int off = 1; off < 256; off <<= 1) {
        int t = s[tid];
        int add = (tid >= off) ? s[tid - off] : 0;
        __syncthreads();
        s[tid] = t + add;
        __syncthreads();
    }
    if (i < SEGS) offs[i] = bpre + (s[tid] - v);
}

// ---------------- CSR fill via LDS cursors + per-chunk slab prefixes ----------------
__global__ __launch_bounds__(256) void fill2_kernel(const int* __restrict__ src,
                                                    const int* __restrict__ dst,
                                                    const int* __restrict__ offs,
                                                    const unsigned short* __restrict__ slab16,
                                                    int* __restrict__ edge_src) {
    __shared__ unsigned int cur[HWORDS];           // 64 KB u16-packed cursors
    int chunk = blockIdx.x, r = blockIdx.y, rg = blockIdx.z;
    for (int w = threadIdx.x; w < HWORDS; w += 256) cur[w] = 0u;
    __syncthreads();
    size_t ebase = (size_t)r * NEDGE + (size_t)chunk * HCHUNK;
    const unsigned short* pre = slab16 + (((size_t)(((3 + r) * 2 + rg) * HC + chunk)) << 15);
    for (int i = threadIdx.x; i < HCHUNK; i += 256) {
        int d = dst[ebase + i];
        if ((d >> 15) == rg) {
            int b = d & 32767;
            unsigned int old = atomicAdd(&cur[b >> 1], 1u << ((b & 1) * 16));
            int local = (int)((old >> ((b & 1) * 16)) & 0xffffu);
            int pos = offs[r * NODES + d] + (int)pre[b] + local;
            edge_src[pos] = src[ebase + i];
        }
    }
}

// ---------------- layer 1 GEMM via MFMA fp16 ----------------
// Wave = 16 nodes x 192 cols (12 C-frags). A = x rows (fp32->fp16 in-reg),
// B = W1t[j][k] fp16. h output fp16 with outnorm folded.
__global__ __launch_bounds__(256, 4) void gemm1_kernel(const float* __restrict__ x,
                                                       const _Float16* __restrict__ W1t,
                                                       const float* __restrict__ outnorm,
                                                       _Float16* __restrict__ h) {
    int lane = threadIdx.x & 63;
    int wv   = threadIdx.x >> 6;
    int m = lane & 15, quad = lane >> 4;
    int n0 = (blockIdx.x * 4 + wv) * 16;
    if (n0 + 16 > NODES) n0 = NODES - 16;          // tail waves duplicate rows (same values)
    const float* xrow = x + (size_t)(n0 + m) * FIN + quad * 8;

    floatx4 acc[12];
#pragma unroll
    for (int t = 0; t < 12; ++t) acc[t] = (floatx4){0.f, 0.f, 0.f, 0.f};

#pragma unroll 1
    for (int ks = 0; ks < 4; ++ks) {               // K step of 32
        float4 xa = *(const float4*)(xrow + ks * 32);
        float4 xb = *(const float4*)(xrow + ks * 32 + 4);
        half8 a;
        a[0] = (_Float16)xa.x; a[1] = (_Float16)xa.y;
        a[2] = (_Float16)xa.z; a[3] = (_Float16)xa.w;
        a[4] = (_Float16)xb.x; a[5] = (_Float16)xb.y;
        a[6] = (_Float16)xb.z; a[7] = (_Float16)xb.w;
#pragma unroll
        for (int jt = 0; jt < 12; ++jt) {          // W1t flat: [192][128]
            const _Float16* bp = W1t + ((size_t)jt * 16 + m) * FIN + ks * 32 + quad * 8;
            half8 b = *(const half8*)bp;
            acc[jt] = __builtin_amdgcn_mfma_f32_16x16x32_f16(a, b, acc[jt], 0, 0, 0);
        }
    }

#pragma unroll
    for (int jt = 0; jt < 12; ++jt) {
        int r = jt >> 2;
        int j = (jt & 3) * 16 + m;                 // D col = lane&15
        _Float16* hb = h + (size_t)r * NODES * FHID;
        const float* on = outnorm + r * NODES;
#pragma unroll
        for (int reg = 0; reg < 4; ++reg) {
            int node = n0 + quad * 4 + reg;        // D row = quad*4+reg
            hb[(size_t)node * FHID + j] = (_Float16)(acc[jt][reg] * on[node]);
        }
    }
}

// ---------------- layer 1 gather: merged 3-relation edge list per dst ----------------
// Wave per dst node; lanes = 8 edges x 8 half8-slots. The three (r,d) segments are
// iterated as ONE logical list (wave-uniform bounds, per-lane cndmask selects
// segment base/weight) -> ~2x fewer dependent idx->gather rounds than per-r loops.
__global__ __launch_bounds__(256) void gather1_kernel(const _Float16* __restrict__ h,
                                                      const int* __restrict__ es,
                                                      const int* __restrict__ offs,
                                                      const int* __restrict__ cnt,
                                                      const float* __restrict__ innorm,
                                                      const float* __restrict__ b1,
                                                      _Float16* __restrict__ B) {
    int lane = threadIdx.x & 63;
    int wv   = threadIdx.x >> 6;
    int d    = blockIdx.x * 4 + wv;
    int q    = lane & 7;                           // half8 slot
    int e8   = lane >> 3;                          // edge-lane
    int c0 = cnt[d], c1 = cnt[NODES + d], c2 = cnt[2 * NODES + d];
    int o0 = offs[d], o1 = offs[NODES + d], o2 = offs[2 * NODES + d];
    float w0 = innorm[d], w1 = innorm[NODES + d], w2 = innorm[2 * NODES + d];
    int c01 = c0 + c1;
    int ctot = c01 + c2;
    const _Float16* h1b = h + (size_t)NODES * FHID;
    const _Float16* h2b = h + 2 * (size_t)NODES * FHID;

    float tot[8] = {0.f, 0.f, 0.f, 0.f, 0.f, 0.f, 0.f, 0.f};
#pragma unroll 2
    for (int g = e8; g < ctot; g += 8) {
        bool in0 = g < c0, in1 = g < c01;
        int addr = in0 ? (o0 + g) : (in1 ? (o1 + g - c0) : (o2 + g - c01));
        float w  = in0 ? w0 : (in1 ? w1 : w2);
        const _Float16* base = in0 ? h : (in1 ? h1b : h2b);
        int idx = es[addr];
        half8 v = *(const half8*)(base + (size_t)idx * FHID + q * 8);
#pragma unroll
        for (int i = 0; i < 8; ++i) tot[i] = fmaf(w, (float)v[i], tot[i]);
    }
#pragma unroll
    for (int i = 0; i < 8; ++i) {
        tot[i] += __shfl_xor(tot[i], 8);
        tot[i] += __shfl_xor(tot[i], 16);
        tot[i] += __shfl_xor(tot[i], 32);
    }
    if (lane < 8) {
        half8 o8;
#pragma unroll
        for (int i = 0; i < 8; ++i) {
            int j = q * 8 + i;
            float bs = b1[j] + b1[FHID + j] + b1[2 * FHID + j];
            o8[i] = (_Float16)fmaxf(tot[i] + bs, 0.f);
        }
        *(half8*)(B + (size_t)d * FHID + q * 8) = o8;
    }
}

// ---------------- layer 2 gather: A2[r][d][:] = innorm * sum_e outnorm[src]*h1[src][:]
__global__ __launch_bounds__(256) void gather2_kernel(const _Float16* __restrict__ h1,
                                                      const int* __restrict__ es,
                                                      const int* __restrict__ offs,
                                                      const int* __restrict__ cnt,
                                                      const float* __restrict__ outnorm,
                                                      const float* __restrict__ innorm,
                                                      _Float16* __restrict__ A2) {
    int lane = threadIdx.x & 63;
    int wv   = threadIdx.x >> 6;
    int d    = blockIdx.x * 4 + wv;
    int r    = blockIdx.y;
    int q    = lane & 7;
    int e8   = lane >> 3;
    int seg = r * NODES + d;
    int o = offs[seg], c = cnt[seg];
    const float* on = outnorm + r * NODES;
    float s0[8] = {0.f, 0.f, 0.f, 0.f, 0.f, 0.f, 0.f, 0.f};
    float s1[8] = {0.f, 0.f, 0.f, 0.f, 0.f, 0.f, 0.f, 0.f};
    int t = 0;
    for (; t + 16 <= c; t += 16) {
        int ia = es[o + t + e8];
        int ib = es[o + t + 8 + e8];
        float wa = on[ia], wb = on[ib];
        half8 va = *(const half8*)(h1 + (size_t)ia * FHID + q * 8);
        half8 vb = *(const half8*)(h1 + (size_t)ib * FHID + q * 8);
#pragma unroll
        for (int i = 0; i < 8; ++i) {
            s0[i] = fmaf(wa, (float)va[i], s0[i]);
            s1[i] = fmaf(wb, (float)vb[i], s1[i]);
        }
    }
    if (t + 8 <= c) {
        int ia = es[o + t + e8];
        float wa = on[ia];
        half8 va = *(const half8*)(h1 + (size_t)ia * FHID + q * 8);
#pragma unroll
        for (int i = 0; i < 8; ++i) s0[i] = fmaf(wa, (float)va[i], s0[i]);
        t += 8;
    }
    int rem = c - t;
    if (e8 < rem) {
        int ia = es[o + t + e8];
        float wa = on[ia];
        half8 va = *(const half8*)(h1 + (size_t)ia * FHID + q * 8);
#pragma unroll
        for (int i = 0; i < 8; ++i) s1[i] = fmaf(wa, (float)va[i], s1[i]);
    }
    float tot[8];
#pragma unroll
    for (int i = 0; i < 8; ++i) {
        tot[i] = s0[i] + s1[i];
        tot[i] += __shfl_xor(tot[i], 8);
        tot[i] += __shfl_xor(tot[i], 16);
        tot[i] += __shfl_xor(tot[i], 32);
    }
    if (lane < 8) {
        float inr = innorm[seg];
        half8 o8;
#pragma unroll
        for (int i = 0; i < 8; ++i) o8[i] = (_Float16)(inr * tot[i]);
        *(half8*)(A2 + (size_t)seg * FHID + q * 8) = o8;
    }
}

// ---------------- layer 2 GEMM via MFMA fp16: out = sum_r A2[r] @ W2[r] + bias
__global__ __launch_bounds__(256, 4) void out_kernel(const _Float16* __restrict__ A2,
                                                     const _Float16* __restrict__ W2t,
                                                     const float* __restrict__ b2,
                                                     float* __restrict__ out) {
    int lane = threadIdx.x & 63;
    int wv   = threadIdx.x >> 6;
    int m = lane & 15, quad = lane >> 4;
    int n0 = (blockIdx.x * 4 + wv) * 16;
    if (n0 + 16 > NODES) n0 = NODES - 16;

    floatx4 acc[4];
#pragma unroll
    for (int t = 0; t < 4; ++t) acc[t] = (floatx4){0.f, 0.f, 0.f, 0.f};

#pragma unroll 1
    for (int kk = 0; kk < 6; ++kk) {               // (rel, 32-K-step)
        int r = kk >> 1, kb = (kk & 1) * 32;
        const _Float16* ap = A2 + ((size_t)r * NODES + n0 + m) * FHID + kb + quad * 8;
        half8 a = *(const half8*)ap;
#pragma unroll
        for (int jt = 0; jt < 4; ++jt) {
            const _Float16* bp = W2t + ((size_t)(r * FOUT + jt * 16 + m)) * FHID + kb + quad * 8;
            half8 b = *(const half8*)bp;
            acc[jt] = __builtin_amdgcn_mfma_f32_16x16x32_f16(a, b, acc[jt], 0, 0, 0);
        }
    }

#pragma unroll
    for (int jt = 0; jt < 4; ++jt) {
        int j = jt * 16 + m;
        float bs = b2[j] + b2[FOUT + j] + b2[2 * FOUT + j];
#pragma unroll
        for (int reg = 0; reg < 4; ++reg) {
            int node = n0 + quad * 4 + reg;
            out[(size_t)node * FOUT + j] = acc[jt][reg] + bs;
        }
    }
}

extern "C" void kernel_launch(void* const* d_in, const int* in_sizes, int n_in,
                              void* d_out, int out_size, void* d_ws, size_t ws_size,
                              hipStream_t stream) {
    const float* x   = (const float*)d_in[0];   // [N,128]
    const float* W1  = (const float*)d_in[1];   // [3,128,64]
    const float* b1  = (const float*)d_in[2];   // [3,64]
    const float* W2  = (const float*)d_in[3];   // [3,64,64]
    const float* b2  = (const float*)d_in[4];   // [3,64]
    const int*   src = (const int*)d_in[5];     // [3,E]
    const int*   dst = (const int*)d_in[6];     // [3,E]
    float* out = (float*)d_out;                 // [N,64]

    // ws: idI | offs | partials | edge_src | outnorm | innorm | W1t | W2t | h | B | A2  (~54.5 MB)
    int*   idI      = (int*)d_ws;
    int*   offs     = idI + SEGS;
    int*   partials = offs + SEGS;
    int*   edge_src = partials + 1024;
    float* outnorm  = (float*)(edge_src + (size_t)RELS * NEDGE);
    float* innorm   = outnorm + SEGS;
    _Float16* W1t   = (_Float16*)(innorm + SEGS);            // [3][64][128]
    _Float16* W2t   = W1t + (size_t)RELS * FHID * FIN;       // [3][64][64]
    _Float16* h     = W2t + (size_t)RELS * FHID * FOUT;      // [3][N][64] fp16
    _Float16* B     = h + (size_t)SEGS * FHID;               // [N][64] fp16
    _Float16* A2    = B + (size_t)NODES * FHID;              // [3][N][64] fp16
    // 25.2 MB slab aliases h|B (consumed by fill2 before gemm1/gather1 write them)
    unsigned int*   slab32 = (unsigned int*)h;
    unsigned short* slab16 = (unsigned short*)h;

    const int GW = ((NODES / 16) + 4) / 4;        // 782 blocks of 4 waves x 16 nodes

    // CSR build + norms + weight convert, no global atomics
    hist_kernel<<<dim3(HC, 6, 2), 256, 0, stream>>>(src, dst, slab32);
    degnorm_kernel<<<(6 * NODES + RELS * FIN * FHID + RELS * FHID * FOUT + 255) / 256,
                     256, 0, stream>>>(slab16, idI, outnorm, innorm, W1, W2, W1t, W2t);
    scan_sums_kernel<<<NBLK, 256, 0, stream>>>(idI, partials);
    scan_write_kernel<<<NBLK, 256, 0, stream>>>(idI, partials, offs);
    fill2_kernel<<<dim3(HC, RELS, 2), 256, 0, stream>>>(src, dst, offs, slab16, edge_src);

    // layer 1
    gemm1_kernel<<<GW, 256, 0, stream>>>(x, W1t, outnorm, h);
    gather1_kernel<<<NODES / 4, 256, 0, stream>>>(h, edge_src, offs, idI, innorm, b1, B);

    // layer 2
    gather2_kernel<<<dim3(NODES / 4, RELS), 256, 0, stream>>>(B, edge_src, offs, idI, outnorm, innorm, A2);
    out_kernel<<<GW, 256, 0, stream>>>(A2, W2t, b2, out);
}

// Round 11
// 310.674 us; speedup vs baseline: 1.3594x; 1.0370x over previous
//
#include <hip/hip_runtime.h>

#define NODES 50000
#define RELS  3
#define NEDGE 600000
#define FIN   128
#define FHID  64
#define FOUT  64
#define SEGS  (RELS * NODES)            // 150000 (rel, dst) segments
#define NBLK  ((SEGS + 255) / 256)      // 586 scan blocks

#define HC     96                       // histogram chunks per edge array
#define HCHUNK (NEDGE / HC)             // 6250 (exact)
#define HBYTES NODES                    // 50000 u8 bins (full node range)
#define HWORDS (HBYTES / 4)             // 12500 u32 words (50 KB LDS)

typedef _Float16 half8 __attribute__((ext_vector_type(8)));
typedef float   floatx4 __attribute__((ext_vector_type(4)));

// ---------------- LDS-staged u8 histogram over FULL node range ----------------
// grid = (chunk, job); job 0..2 = src[r] (out-deg), 3..5 = dst[r] (in-deg).
// Per-(chunk,bin) count <= ~10 << 255 so u8 cannot overflow.
__global__ __launch_bounds__(256) void hist_kernel(const int* __restrict__ src,
                                                   const int* __restrict__ dst,
                                                   unsigned int* __restrict__ slab32) {
    __shared__ unsigned int bins[HWORDS];          // 50 KB, u8-packed counts
    int chunk = blockIdx.x, job = blockIdx.y;
    const int* arr = (job < 3 ? src + (size_t)job * NEDGE
                              : dst + (size_t)(job - 3) * NEDGE) + (size_t)chunk * HCHUNK;
    for (int w = threadIdx.x; w < HWORDS; w += 256) bins[w] = 0u;
    __syncthreads();
    for (int i = threadIdx.x; i < HCHUNK; i += 256) {
        int v = arr[i];
        atomicAdd(&bins[v >> 2], 1u << ((v & 3) * 8));       // LDS, no return
    }
    __syncthreads();
    unsigned int* out = slab32 + ((size_t)(job * HC + chunk)) * HWORDS;
    for (int w = threadIdx.x; w < HWORDS; w += 256) out[w] = bins[w];
}

// ---------------- slab reduce -> degrees/norms (+ fused weight fp16 transpose)
// dst-jobs: rewrite each chunk's count as per-chunk exclusive prefix (fits u8).
__global__ __launch_bounds__(256) void degnorm_kernel(unsigned char* __restrict__ slab8,
                                                      int* __restrict__ idI,
                                                      float* __restrict__ outnorm,
                                                      float* __restrict__ innorm,
                                                      const float* __restrict__ W1,
                                                      const float* __restrict__ W2,
                                                      _Float16* __restrict__ W1t,
                                                      _Float16* __restrict__ W2t) {
    int gid = blockIdx.x * 256 + threadIdx.x;
    if (gid < 6 * NODES) {
        int j = gid / NODES, b = gid - j * NODES;
        size_t base = (size_t)j * HC * HBYTES + b;
        if (j < 3) {
            int sum = 0;
#pragma unroll 4
            for (int c = 0; c < HC; ++c) sum += slab8[base + (size_t)c * HBYTES];
            outnorm[j * NODES + b] = rsqrtf(fmaxf((float)sum, 1.0f));
        } else {
            int run = 0;
#pragma unroll 4
            for (int c = 0; c < HC; ++c) {
                size_t idx = base + (size_t)c * HBYTES;
                int v = slab8[idx];
                slab8[idx] = (unsigned char)run;             // prefix <= in-deg (~40) fits u8
                run += v;
            }
            idI[(j - 3) * NODES + b] = run;
            innorm[(j - 3) * NODES + b] = rsqrtf(fmaxf((float)run, 1.0f));
        }
        return;
    }
    int g2 = gid - 6 * NODES;
    if (g2 < RELS * FIN * FHID) {                  // W1 -> fp16 [r][j][k]
        int r = g2 / (FIN * FHID);
        int rem = g2 - r * FIN * FHID;
        int k = rem / FHID, j = rem - k * FHID;
        W1t[((size_t)r * FHID + j) * FIN + k] = (_Float16)W1[g2];
        return;
    }
    int g3 = g2 - RELS * FIN * FHID;
    if (g3 < RELS * FHID * FOUT) {                 // W2 -> fp16 [r][j][k]
        int r = g3 / (FHID * FOUT);
        int rem = g3 - r * FHID * FOUT;
        int k = rem / FOUT, j = rem - k * FOUT;
        W2t[((size_t)r * FOUT + j) * FHID + k] = (_Float16)W2[g3];
    }
}

// ---------------- scan step 1: per-block sums ----------------
__global__ __launch_bounds__(256) void scan_sums_kernel(const int* __restrict__ idI,
                                                        int* __restrict__ partials) {
    __shared__ int s[256];
    int i = blockIdx.x * 256 + threadIdx.x;
    s[threadIdx.x] = (i < SEGS) ? idI[i] : 0;
    __syncthreads();
    for (int off = 128; off > 0; off >>= 1) {
        if (threadIdx.x < off) s[threadIdx.x] += s[threadIdx.x + off];
        __syncthreads();
    }
    if (threadIdx.x == 0) partials[blockIdx.x] = s[0];
}

// ---------------- scan step 2: re-scan partials in LDS, then block scan ----------------
__global__ __launch_bounds__(256) void scan_write_kernel(const int* __restrict__ idI,
                                                         const int* __restrict__ partials,
                                                         int* __restrict__ offs) {
    __shared__ int sp[1024];
    __shared__ int s[256];
    int tid = threadIdx.x;
    for (int i = tid; i < 1024; i += 256) sp[i] = (i < NBLK) ? partials[i] : 0;
    __syncthreads();
    for (int off = 1; off < 1024; off <<= 1) {
        int v[4];
#pragma unroll
        for (int k = 0; k < 4; ++k) { int i = tid + k * 256; v[k] = (i >= off) ? sp[i - off] : 0; }
        __syncthreads();
#pragma unroll
        for (int k = 0; k < 4; ++k) sp[tid + k * 256] += v[k];
        __syncthreads();
    }
    int bpre = (blockIdx.x == 0) ? 0 : sp[blockIdx.x - 1];   // exclusive prefix of this block
    int i = blockIdx.x * 256 + tid;
    int v = (i < SEGS) ? idI[i] : 0;
    s[tid] = v;
    __syncthreads();
    for (int off = 1; off < 256; off <<= 1) {
        int t = s[tid];
        int add = (tid >= off) ? s[tid - off] : 0;
        __syncthreads();
        s[tid] = t + add;
        __syncthreads();
    }
    if (i < SEGS) offs[i] = bpre + (s[tid] - v);
}

// ---------------- CSR fill: u8 LDS cursors + u8 per-chunk prefixes, one pass ----------------
__global__ __launch_bounds__(256) void fill2_kernel(const int* __restrict__ src,
                                                    const int* __restrict__ dst,
                                                    const int* __restrict__ offs,
                                                    const unsigned char* __restrict__ slab8,
                                                    unsigned short* __restrict__ edge_src) {
    __shared__ unsigned int cur[HWORDS];           // 50 KB u8-packed cursors
    int chunk = blockIdx.x, r = blockIdx.y;
    for (int w = threadIdx.x; w < HWORDS; w += 256) cur[w] = 0u;
    __syncthreads();
    size_t ebase = (size_t)r * NEDGE + (size_t)chunk * HCHUNK;
    const unsigned char* pre = slab8 + ((size_t)((3 + r) * HC + chunk)) * HBYTES;
    for (int i = threadIdx.x; i < HCHUNK; i += 256) {
        int d = dst[ebase + i];
        unsigned int old = atomicAdd(&cur[d >> 2], 1u << ((d & 3) * 8));
        int local = (int)((old >> ((d & 3) * 8)) & 0xffu);
        int pos = offs[r * NODES + d] + (int)pre[d] + local;
        edge_src[pos] = (unsigned short)src[ebase + i];
    }
}

// ---------------- layer 1 GEMM via MFMA fp16 ----------------
// Wave = 16 nodes x 192 cols (12 C-frags). A = x rows (fp32->fp16 in-reg),
// B = W1t[j][k] fp16. h output fp16 with outnorm folded.
__global__ __launch_bounds__(256, 4) void gemm1_kernel(const float* __restrict__ x,
                                                       const _Float16* __restrict__ W1t,
                                                       const float* __restrict__ outnorm,
                                                       _Float16* __restrict__ h) {
    int lane = threadIdx.x & 63;
    int wv   = threadIdx.x >> 6;
    int m = lane & 15, quad = lane >> 4;
    int n0 = (blockIdx.x * 4 + wv) * 16;
    if (n0 + 16 > NODES) n0 = NODES - 16;          // tail waves duplicate rows (same values)
    const float* xrow = x + (size_t)(n0 + m) * FIN + quad * 8;

    floatx4 acc[12];
#pragma unroll
    for (int t = 0; t < 12; ++t) acc[t] = (floatx4){0.f, 0.f, 0.f, 0.f};

#pragma unroll 1
    for (int ks = 0; ks < 4; ++ks) {               // K step of 32
        float4 xa = *(const float4*)(xrow + ks * 32);
        float4 xb = *(const float4*)(xrow + ks * 32 + 4);
        half8 a;
        a[0] = (_Float16)xa.x; a[1] = (_Float16)xa.y;
        a[2] = (_Float16)xa.z; a[3] = (_Float16)xa.w;
        a[4] = (_Float16)xb.x; a[5] = (_Float16)xb.y;
        a[6] = (_Float16)xb.z; a[7] = (_Float16)xb.w;
#pragma unroll
        for (int jt = 0; jt < 12; ++jt) {          // W1t flat: [192][128]
            const _Float16* bp = W1t + ((size_t)jt * 16 + m) * FIN + ks * 32 + quad * 8;
            half8 b = *(const half8*)bp;
            acc[jt] = __builtin_amdgcn_mfma_f32_16x16x32_f16(a, b, acc[jt], 0, 0, 0);
        }
    }

#pragma unroll
    for (int jt = 0; jt < 12; ++jt) {
        int r = jt >> 2;
        int j = (jt & 3) * 16 + m;                 // D col = lane&15
        _Float16* hb = h + (size_t)r * NODES * FHID;
        const float* on = outnorm + r * NODES;
#pragma unroll
        for (int reg = 0; reg < 4; ++reg) {
            int node = n0 + quad * 4 + reg;        // D row = quad*4+reg
            hb[(size_t)node * FHID + j] = (_Float16)(acc[jt][reg] * on[node]);
        }
    }
}

// ---------------- layer 1 gather: merged 3-relation edge list per dst ----------------
__global__ __launch_bounds__(256) void gather1_kernel(const _Float16* __restrict__ h,
                                                      const unsigned short* __restrict__ es,
                                                      const int* __restrict__ offs,
                                                      const int* __restrict__ cnt,
                                                      const float* __restrict__ innorm,
                                                      const float* __restrict__ b1,
                                                      _Float16* __restrict__ B) {
    int lane = threadIdx.x & 63;
    int wv   = threadIdx.x >> 6;
    int d    = blockIdx.x * 4 + wv;
    int q    = lane & 7;                           // half8 slot
    int e8   = lane >> 3;                          // edge-lane
    int c0 = cnt[d], c1 = cnt[NODES + d], c2 = cnt[2 * NODES + d];
    int o0 = offs[d], o1 = offs[NODES + d], o2 = offs[2 * NODES + d];
    float w0 = innorm[d], w1 = innorm[NODES + d], w2 = innorm[2 * NODES + d];
    int c01 = c0 + c1;
    int ctot = c01 + c2;
    const _Float16* h1b = h + (size_t)NODES * FHID;
    const _Float16* h2b = h + 2 * (size_t)NODES * FHID;

    float tot[8] = {0.f, 0.f, 0.f, 0.f, 0.f, 0.f, 0.f, 0.f};
#pragma unroll 2
    for (int g = e8; g < ctot; g += 8) {
        bool in0 = g < c0, in1 = g < c01;
        int addr = in0 ? (o0 + g) : (in1 ? (o1 + g - c0) : (o2 + g - c01));
        float w  = in0 ? w0 : (in1 ? w1 : w2);
        const _Float16* base = in0 ? h : (in1 ? h1b : h2b);
        int idx = es[addr];
        half8 v = *(const half8*)(base + (size_t)idx * FHID + q * 8);
#pragma unroll
        for (int i = 0; i < 8; ++i) tot[i] = fmaf(w, (float)v[i], tot[i]);
    }
#pragma unroll
    for (int i = 0; i < 8; ++i) {
        tot[i] += __shfl_xor(tot[i], 8);
        tot[i] += __shfl_xor(tot[i], 16);
        tot[i] += __shfl_xor(tot[i], 32);
    }
    if (lane < 8) {
        half8 o8;
#pragma unroll
        for (int i = 0; i < 8; ++i) {
            int j = q * 8 + i;
            float bs = b1[j] + b1[FHID + j] + b1[2 * FHID + j];
            o8[i] = (_Float16)fmaxf(tot[i] + bs, 0.f);
        }
        *(half8*)(B + (size_t)d * FHID + q * 8) = o8;
    }
}

// ---------------- layer 2 gather: A2[r][d][:] = innorm * sum_e outnorm[src]*h1[src][:]
__global__ __launch_bounds__(256) void gather2_kernel(const _Float16* __restrict__ h1,
                                                      const unsigned short* __restrict__ es,
                                                      const int* __restrict__ offs,
                                                      const int* __restrict__ cnt,
                                                      const float* __restrict__ outnorm,
                                                      const float* __restrict__ innorm,
                                                      _Float16* __restrict__ A2) {
    int lane = threadIdx.x & 63;
    int wv   = threadIdx.x >> 6;
    int d    = blockIdx.x * 4 + wv;
    int r    = blockIdx.y;
    int q    = lane & 7;
    int e8   = lane >> 3;
    int seg = r * NODES + d;
    int o = offs[seg], c = cnt[seg];
    const float* on = outnorm + r * NODES;
    float s0[8] = {0.f, 0.f, 0.f, 0.f, 0.f, 0.f, 0.f, 0.f};
    float s1[8] = {0.f, 0.f, 0.f, 0.f, 0.f, 0.f, 0.f, 0.f};
    int t = 0;
    for (; t + 16 <= c; t += 16) {
        int ia = es[o + t + e8];
        int ib = es[o + t + 8 + e8];
        float wa = on[ia], wb = on[ib];
        half8 va = *(const half8*)(h1 + (size_t)ia * FHID + q * 8);
        half8 vb = *(const half8*)(h1 + (size_t)ib * FHID + q * 8);
#pragma unroll
        for (int i = 0; i < 8; ++i) {
            s0[i] = fmaf(wa, (float)va[i], s0[i]);
            s1[i] = fmaf(wb, (float)vb[i], s1[i]);
        }
    }
    if (t + 8 <= c) {
        int ia = es[o + t + e8];
        float wa = on[ia];
        half8 va = *(const half8*)(h1 + (size_t)ia * FHID + q * 8);
#pragma unroll
        for (int i = 0; i < 8; ++i) s0[i] = fmaf(wa, (float)va[i], s0[i]);
        t += 8;
    }
    int rem = c - t;
    if (e8 < rem) {
        int ia = es[o + t + e8];
        float wa = on[ia];
        half8 va = *(const half8*)(h1 + (size_t)ia * FHID + q * 8);
#pragma unroll
        for (int i = 0; i < 8; ++i) s1[i] = fmaf(wa, (float)va[i], s1[i]);
    }
    float tot[8];
#pragma unroll
    for (int i = 0; i < 8; ++i) {
        tot[i] = s0[i] + s1[i];
        tot[i] += __shfl_xor(tot[i], 8);
        tot[i] += __shfl_xor(tot[i], 16);
        tot[i] += __shfl_xor(tot[i], 32);
    }
    if (lane < 8) {
        float inr = innorm[seg];
        half8 o8;
#pragma unroll
        for (int i = 0; i < 8; ++i) o8[i] = (_Float16)(inr * tot[i]);
        *(half8*)(A2 + (size_t)seg * FHID + q * 8) = o8;
    }
}

// ---------------- layer 2 GEMM via MFMA fp16: out = sum_r A2[r] @ W2[r] + bias
__global__ __launch_bounds__(256, 4) void out_kernel(const _Float16* __restrict__ A2,
                                                     const _Float16* __restrict__ W2t,
                                                     const float* __restrict__ b2,
                                                     float* __restrict__ out) {
    int lane = threadIdx.x & 63;
    int wv   = threadIdx.x >> 6;
    int m = lane & 15, quad = lane >> 4;
    int n0 = (blockIdx.x * 4 + wv) * 16;
    if (n0 + 16 > NODES) n0 = NODES - 16;

    floatx4 acc[4];
#pragma unroll
    for (int t = 0; t < 4; ++t) acc[t] = (floatx4){0.f, 0.f, 0.f, 0.f};

#pragma unroll 1
    for (int kk = 0; kk < 6; ++kk) {               // (rel, 32-K-step)
        int r = kk >> 1, kb = (kk & 1) * 32;
        const _Float16* ap = A2 + ((size_t)r * NODES + n0 + m) * FHID + kb + quad * 8;
        half8 a = *(const half8*)ap;
#pragma unroll
        for (int jt = 0; jt < 4; ++jt) {
            const _Float16* bp = W2t + ((size_t)(r * FOUT + jt * 16 + m)) * FHID + kb + quad * 8;
            half8 b = *(const half8*)bp;
            acc[jt] = __builtin_amdgcn_mfma_f32_16x16x32_f16(a, b, acc[jt], 0, 0, 0);
        }
    }

#pragma unroll
    for (int jt = 0; jt < 4; ++jt) {
        int j = jt * 16 + m;
        float bs = b2[j] + b2[FOUT + j] + b2[2 * FOUT + j];
#pragma unroll
        for (int reg = 0; reg < 4; ++reg) {
            int node = n0 + quad * 4 + reg;
            out[(size_t)node * FOUT + j] = acc[jt][reg] + bs;
        }
    }
}

extern "C" void kernel_launch(void* const* d_in, const int* in_sizes, int n_in,
                              void* d_out, int out_size, void* d_ws, size_t ws_size,
                              hipStream_t stream) {
    const float* x   = (const float*)d_in[0];   // [N,128]
    const float* W1  = (const float*)d_in[1];   // [3,128,64]
    const float* b1  = (const float*)d_in[2];   // [3,64]
    const float* W2  = (const float*)d_in[3];   // [3,64,64]
    const float* b2  = (const float*)d_in[4];   // [3,64]
    const int*   src = (const int*)d_in[5];     // [3,E]
    const int*   dst = (const int*)d_in[6];     // [3,E]
    float* out = (float*)d_out;                 // [N,64]

    // ws: idI | offs | partials | edge_src(u16) | outnorm | innorm | W1t | W2t | h | B | A2
    int*   idI      = (int*)d_ws;
    int*   offs     = idI + SEGS;
    int*   partials = offs + SEGS;
    unsigned short* edge_src = (unsigned short*)(partials + 1024);           // [3E] u16
    float* outnorm  = (float*)(edge_src + (size_t)RELS * NEDGE);
    float* innorm   = outnorm + SEGS;
    _Float16* W1t   = (_Float16*)(innorm + SEGS);            // [3][64][128]
    _Float16* W2t   = W1t + (size_t)RELS * FHID * FIN;       // [3][64][64]
    _Float16* h     = W2t + (size_t)RELS * FHID * FOUT;      // [3][N][64] fp16
    _Float16* B     = h + (size_t)SEGS * FHID;               // [N][64] fp16
    _Float16* A2    = B + (size_t)NODES * FHID;              // [3][N][64] fp16
    // u8 slab (6*HC*50000 = 28.8 MB) aliases h|B|A2-head: fully consumed by
    // fill2 before gemm1/gather1/gather2 write those regions.
    unsigned int*  slab32 = (unsigned int*)h;
    unsigned char* slab8  = (unsigned char*)h;

    const int GW = ((NODES / 16) + 4) / 4;        // 782 blocks of 4 waves x 16 nodes

    // CSR build + norms + weight convert, no global atomics, single edge pass
    hist_kernel<<<dim3(HC, 6), 256, 0, stream>>>(src, dst, slab32);
    degnorm_kernel<<<(6 * NODES + RELS * FIN * FHID + RELS * FHID * FOUT + 255) / 256,
                     256, 0, stream>>>(slab8, idI, outnorm, innorm, W1, W2, W1t, W2t);
    scan_sums_kernel<<<NBLK, 256, 0, stream>>>(idI, partials);
    scan_write_kernel<<<NBLK, 256, 0, stream>>>(idI, partials, offs);
    fill2_kernel<<<dim3(HC, RELS), 256, 0, stream>>>(src, dst, offs, slab8, edge_src);

    // layer 1
    gemm1_kernel<<<GW, 256, 0, stream>>>(x, W1t, outnorm, h);
    gather1_kernel<<<NODES / 4, 256, 0, stream>>>(h, edge_src, offs, idI, innorm, b1, B);

    // layer 2
    gather2_kernel<<<dim3(NODES / 4, RELS), 256, 0, stream>>>(B, edge_src, offs, idI, outnorm, innorm, A2);
    out_kernel<<<GW, 256, 0, stream>>>(A2, W2t, b2, out);
}